// Round 4
// baseline (877.410 us; speedup 1.0000x reference)
//
#include <hip/hip_runtime.h>
#include <math.h>

#define E 192
#define DI 384
#define S 16
#define R 12
#define DEPTH 4
#define P 400
#define NC 20
#define BATCH 32
#define L 401
#define NTOK (BATCH * L)   // 12832
#define CH 32
#define NCH 13             // ceil(401/32)

using short8 = __attribute__((ext_vector_type(8))) short;
using float4v = __attribute__((ext_vector_type(4))) float;

__device__ __forceinline__ float siluf(float x) {
    return x / (1.f + __expf(-x));
}
__device__ __forceinline__ float softplusf(float x) {
    return (x > 20.f) ? x : log1pf(__expf(x));
}
// f32 -> bf16 round-to-nearest-even (bit-level; no __hip_bfloat16 dep)
__device__ __forceinline__ unsigned short f2bf(float x) {
    unsigned int u = __float_as_uint(x);
    unsigned int r = 0x7fffu + ((u >> 16) & 1u);
    return (unsigned short)((u + r) >> 16);
}

// ---------------------------------------------------------------------------
// K0: patch embed + pos + depthwise conv3 + cls token  -> resid[b,l,e]
// ---------------------------------------------------------------------------
__global__ void k_embed(const float* __restrict__ imgs, const float* __restrict__ patch_w,
                        const float* __restrict__ patch_b, const float* __restrict__ cls_token,
                        const float* __restrict__ pos_embed, const float* __restrict__ cnn_w,
                        const float* __restrict__ cnn_b, float* __restrict__ resid) {
    int idx = blockIdx.x * blockDim.x + threadIdx.x;
    if (idx >= NTOK * E) return;
    int e = idx % E;
    int bl = idx / E;
    int l = bl % L;
    int b = bl / L;
    float out;
    if (l == P) {
        out = cls_token[e] + pos_embed[(size_t)P * E + e];
    } else {
        float w0 = patch_w[e * 4 + 0], w1 = patch_w[e * 4 + 1];
        float w2 = patch_w[e * 4 + 2], w3 = patch_w[e * 4 + 3];
        float pb = patch_b[e];
        const float* ib = imgs + (size_t)b * 1600;
        auto xe = [&](int ll) -> float {
            const float* ip = ib + ll * 4;
            return ip[0] * w0 + ip[1] * w1 + ip[2] * w2 + ip[3] * w3 + pb +
                   pos_embed[(size_t)ll * E + e];
        };
        float c0 = cnn_w[e * 3 + 0], c1 = cnn_w[e * 3 + 1], c2 = cnn_w[e * 3 + 2];
        float acc = cnn_b[e] + xe(l) * c1;
        if (l > 0) acc += xe(l - 1) * c0;
        if (l < P - 1) acc += xe(l + 1) * c2;
        out = acc;
    }
    resid[idx] = out;
}

// ---------------------------------------------------------------------------
// K1: (optional resid += hidden) then hn = rmsnorm(resid)*w -> bf16
// ---------------------------------------------------------------------------
template <bool ADD>
__global__ void k_rmsnorm(const float* __restrict__ hidden, float* __restrict__ resid,
                          unsigned short* __restrict__ hn, const float* __restrict__ w) {
    int wave = blockIdx.x * (blockDim.x >> 6) + (threadIdx.x >> 6);
    int lane = threadIdx.x & 63;
    if (wave >= NTOK) return;
    size_t base = (size_t)wave * E;
    float v[3];
    float ss = 0.f;
#pragma unroll
    for (int j = 0; j < 3; j++) {
        int e = lane + j * 64;
        float r = resid[base + e];
        if (ADD) {
            r += hidden[base + e];
            resid[base + e] = r;
        }
        v[j] = r;
        ss += r * r;
    }
#pragma unroll
    for (int off = 32; off > 0; off >>= 1) ss += __shfl_xor(ss, off, 64);
    float scale = rsqrtf(ss * (1.f / (float)E) + 1e-5f);
#pragma unroll
    for (int j = 0; j < 3; j++) {
        int e = lane + j * 64;
        hn[base + e] = f2bf(v[j] * scale * w[e]);
    }
}

// ---------------------------------------------------------------------------
// K_cvt: f32 -> bf16 (weights, once per launch)
// ---------------------------------------------------------------------------
__global__ void k_cvt(const float* __restrict__ src, unsigned short* __restrict__ dst, int n) {
    int idx = blockIdx.x * blockDim.x + threadIdx.x;
    if (idx < n) dst[idx] = f2bf(src[idx]);
}

// K_preA: negA = -exp(A_log), all layers at once (DEPTH*DI*S elems)
__global__ void k_preA(const float* __restrict__ A_log, float* __restrict__ negA, int n) {
    int idx = blockIdx.x * blockDim.x + threadIdx.x;
    if (idx < n) negA[idx] = -__expf(A_log[idx]);
}

// ---------------------------------------------------------------------------
// K2: bf16 MFMA GEMM  C[M,N](f32) = A[M,K](bf16) * W[N,K](bf16)^T
// block 256 (4 waves, 2x2), tile BM x 64, BK=64. Wave tile (BM/2) x 32.
// ---------------------------------------------------------------------------
template <int BM>
__global__ __launch_bounds__(256) void k_gemm_bf16(const unsigned short* __restrict__ A,
                                                   const unsigned short* __restrict__ W,
                                                   float* __restrict__ C, int M, int N, int K) {
    constexpr int BN = 64, BK = 64, PADK = BK + 8;
    constexpr int MT = BM / 32;  // 16-row mfma tiles per wave in M
    __shared__ unsigned short As[BM][PADK];
    __shared__ unsigned short Bs[BN][PADK];
    int tid = threadIdx.x;
    int m0 = blockIdx.y * BM, n0 = blockIdx.x * BN;
    int wave = tid >> 6, lane = tid & 63;
    int row16 = lane & 15, quad = lane >> 4;
    int wm0 = (wave >> 1) * (BM / 2), wn0 = (wave & 1) * 32;

    float4v acc[MT][2];
#pragma unroll
    for (int i = 0; i < MT; i++)
#pragma unroll
        for (int j = 0; j < 2; j++) acc[i][j] = (float4v){0.f, 0.f, 0.f, 0.f};

    for (int k0 = 0; k0 < K; k0 += BK) {
        // stage A: BM x 64 elems, BM/32 passes of 256 thr x 8
#pragma unroll
        for (int p = 0; p < MT; p++) {
            int idx = (p * 256 + tid) * 8;
            int row = idx / BK, col = idx % BK;
            int gm = m0 + row;
            short8 v;
            if (gm < M)
                v = *(const short8*)&A[(size_t)gm * K + k0 + col];
            else
                v = (short8)0;
            *(short8*)&As[row][col] = v;
        }
        // stage B: 64x64 elems, 2 passes
#pragma unroll
        for (int p = 0; p < 2; p++) {
            int idx = (p * 256 + tid) * 8;
            int row = idx / BK, col = idx % BK;
            int gn = n0 + row;
            short8 v;
            if (gn < N)
                v = *(const short8*)&W[(size_t)gn * K + k0 + col];
            else
                v = (short8)0;
            *(short8*)&Bs[row][col] = v;
        }
        __syncthreads();
#pragma unroll
        for (int kk = 0; kk < BK; kk += 32) {
            int koff = kk + quad * 8;
            short8 af[MT], bfr[2];
#pragma unroll
            for (int i = 0; i < MT; i++)
                af[i] = *(const short8*)&As[wm0 + i * 16 + row16][koff];
#pragma unroll
            for (int j = 0; j < 2; j++)
                bfr[j] = *(const short8*)&Bs[wn0 + j * 16 + row16][koff];
#pragma unroll
            for (int i = 0; i < MT; i++)
#pragma unroll
                for (int j = 0; j < 2; j++)
                    acc[i][j] = __builtin_amdgcn_mfma_f32_16x16x32_bf16(af[i], bfr[j],
                                                                        acc[i][j], 0, 0, 0);
        }
        __syncthreads();
    }
    // write out: D layout row=quad*4+r, col=row16
#pragma unroll
    for (int i = 0; i < MT; i++) {
#pragma unroll
        for (int j = 0; j < 2; j++) {
#pragma unroll
            for (int r = 0; r < 4; r++) {
                int m = m0 + wm0 + i * 16 + quad * 4 + r;
                int n = n0 + wn0 + j * 16 + row16;
                if (m < M && n < N) C[(size_t)m * N + n] = acc[i][j][r];
            }
        }
    }
}

// ---------------------------------------------------------------------------
// K3: causal depthwise conv4 + SiLU over xm = xz[..., :DI] -> xc (f32 + bf16)
// ---------------------------------------------------------------------------
__global__ void k_conv(const float* __restrict__ xz, const float* __restrict__ cw,
                       const float* __restrict__ cb, float* __restrict__ xc,
                       unsigned short* __restrict__ xc_bf) {
    int idx = blockIdx.x * blockDim.x + threadIdx.x;
    if (idx >= NTOK * DI) return;
    int d = idx % DI;
    int bl = idx / DI;
    int l = bl % L;
    int b = bl / L;
    const float* base = xz + (size_t)b * L * (2 * DI) + d;
    float acc = cb[d];
#pragma unroll
    for (int k = 0; k < 4; k++) {
        int ll = l - 3 + k;
        if (ll >= 0) acc += base[(size_t)ll * (2 * DI)] * cw[d * 4 + k];
    }
    float v = siluf(acc);
    xc[idx] = v;
    xc_bf[idx] = f2bf(v);
}

// ---------------------------------------------------------------------------
// K4a: chunk-local scan with dt_proj fused. h starts at 0. Emits per-token
// y_local (C.h_local + u*D) and dtcum (running sum of dt), plus chunk h_end.
// grid (NCH, BATCH) x 384 threads.
// ---------------------------------------------------------------------------
__global__ void k_scanA(const float* __restrict__ xc, const float* __restrict__ xdb,
                        const float* __restrict__ negA, const float* __restrict__ dtw,
                        const float* __restrict__ dtb, const float* __restrict__ Dskip,
                        float* __restrict__ ylocal, float* __restrict__ dtcum,
                        float* __restrict__ hend) {
    int d = threadIdx.x;
    int ch = blockIdx.x;
    int b = blockIdx.y;
    int t0 = ch * CH;
    int t1 = min(t0 + CH, L);
    float a[S];
#pragma unroll
    for (int n = 0; n < S; n++) a[n] = negA[d * S + n];
    float wdt[R];
#pragma unroll
    for (int r = 0; r < R; r++) wdt[r] = dtw[d * R + r];
    float bias = dtb[d];
    float dsk = Dskip[d];
    float h[S] = {};
    float dts = 0.f;
    for (int t = t0; t < t1; t++) {
        size_t tok = (size_t)b * L + t;
        const float* row = xdb + tok * 44;   // wave-uniform address -> s_loads
        float dtacc = bias;
#pragma unroll
        for (int r = 0; r < R; r++) dtacc += row[r] * wdt[r];
        float dtv = softplusf(dtacc);
        dts += dtv;
        float u = xc[tok * DI + d];
        float dtu = dtv * u;
        float y = u * dsk;
#pragma unroll
        for (int n = 0; n < S; n++) {
            float dA = __expf(dtv * a[n]);
            h[n] = dA * h[n] + dtu * row[R + n];
            y += h[n] * row[R + S + n];
        }
        ylocal[tok * DI + d] = y;
        dtcum[tok * DI + d] = dts;
    }
    size_t o = (((size_t)b * NCH + ch) * DI + d) * S;
#pragma unroll
    for (int n = 0; n < S; n++) hend[o + n] = h[n];
}

// ---------------------------------------------------------------------------
// K4b: combine chunk prefixes serially (13 chunks) -> h_init per chunk.
// ---------------------------------------------------------------------------
__global__ void k_scanB(const float* __restrict__ hend, const float* __restrict__ dtcum,
                        const float* __restrict__ negA, float* __restrict__ hinit) {
    int idx = blockIdx.x * blockDim.x + threadIdx.x;
    if (idx >= BATCH * DI) return;
    int d = idx % DI;
    int b = idx / DI;
    float a[S];
#pragma unroll
    for (int n = 0; n < S; n++) a[n] = negA[d * S + n];
    float h[S] = {};
    for (int ch = 0; ch < NCH; ch++) {
        size_t o = (((size_t)b * NCH + ch) * DI + d) * S;
#pragma unroll
        for (int n = 0; n < S; n++) hinit[o + n] = h[n];
        int tlast = min(ch * CH + CH, L) - 1;
        float dts = dtcum[((size_t)b * L + tlast) * DI + d];
#pragma unroll
        for (int n = 0; n < S; n++) h[n] = __expf(dts * a[n]) * h[n] + hend[o + n];
    }
}

// ---------------------------------------------------------------------------
// K4c: fully-parallel fixup: y = (y_local + sum_n c_n exp(a_n dtcum) h0_n)
//      * silu(z)  -> bf16. One thread per (tok,d); no sequential loop.
// ---------------------------------------------------------------------------
__global__ void k_fixup(const float* __restrict__ xz, const float* __restrict__ xdb,
                        const float* __restrict__ negA, const float* __restrict__ hinit,
                        const float* __restrict__ ylocal, const float* __restrict__ dtcum,
                        unsigned short* __restrict__ y_bf) {
    int idx = blockIdx.x * blockDim.x + threadIdx.x;
    if (idx >= NTOK * DI) return;
    int d = idx % DI;
    int tok = idx / DI;
    int l = tok % L;
    int b = tok / L;
    int ch = l / CH;  // wave-uniform (DI divisible by 64)
    float y = ylocal[idx];
    if (ch != 0) {
        float dts = dtcum[idx];
        const float* h0 = hinit + (((size_t)b * NCH + ch) * DI + d) * S;
        const float* an = negA + d * S;
        const float* cv = xdb + (size_t)tok * 44 + R + S;
        float corr = 0.f;
#pragma unroll
        for (int n = 0; n < S; n++) corr += cv[n] * __expf(an[n] * dts) * h0[n];
        y += corr;
    }
    float z = xz[(size_t)tok * (2 * DI) + DI + d];
    y_bf[idx] = f2bf(y * siluf(z));
}

// ---------------------------------------------------------------------------
// K5: final rmsnorm of token 400 of (resid+hidden), then head matmul -> out
// ---------------------------------------------------------------------------
__global__ void k_head(const float* __restrict__ resid, const float* __restrict__ hidden,
                       const float* __restrict__ norm_f_w, const float* __restrict__ head_w,
                       const float* __restrict__ head_b, float* __restrict__ out) {
    __shared__ float v[E];
    int b = blockIdx.x;
    int lane = threadIdx.x;
    size_t base = ((size_t)b * L + P) * E;
    float loc[3];
    float ss = 0.f;
#pragma unroll
    for (int j = 0; j < 3; j++) {
        int e = lane + j * 64;
        float x = resid[base + e] + hidden[base + e];
        loc[j] = x;
        ss += x * x;
    }
#pragma unroll
    for (int off = 32; off > 0; off >>= 1) ss += __shfl_xor(ss, off, 64);
    float scale = rsqrtf(ss * (1.f / (float)E) + 1e-5f);
#pragma unroll
    for (int j = 0; j < 3; j++) {
        int e = lane + j * 64;
        v[e] = loc[j] * scale * norm_f_w[e];
    }
    __syncthreads();
    if (lane < NC) {
        float acc = head_b[lane];
        for (int e = 0; e < E; e++) acc += v[e] * head_w[lane * E + e];
        out[b * NC + lane] = acc;
    }
}

// ---------------------------------------------------------------------------
extern "C" void kernel_launch(void* const* d_in, const int* in_sizes, int n_in,
                              void* d_out, int out_size, void* d_ws, size_t ws_size,
                              hipStream_t stream) {
    const float* imgs      = (const float*)d_in[0];
    const float* patch_w   = (const float*)d_in[1];
    const float* patch_b   = (const float*)d_in[2];
    const float* cls_token = (const float*)d_in[3];
    const float* pos_embed = (const float*)d_in[4];
    const float* cnn_w     = (const float*)d_in[5];
    const float* cnn_b     = (const float*)d_in[6];
    const float* norm_w    = (const float*)d_in[7];
    const float* in_proj_w = (const float*)d_in[8];
    const float* conv_w    = (const float*)d_in[9];
    const float* conv_b    = (const float*)d_in[10];
    const float* x_proj_w  = (const float*)d_in[11];
    const float* dt_proj_w = (const float*)d_in[12];
    const float* dt_proj_b = (const float*)d_in[13];
    const float* A_log     = (const float*)d_in[14];
    const float* Dskip     = (const float*)d_in[15];
    const float* out_proj_w= (const float*)d_in[16];
    const float* norm_f_w  = (const float*)d_in[17];
    const float* head_w    = (const float*)d_in[18];
    const float* head_b    = (const float*)d_in[19];

    float* ws = (float*)d_ws;
    size_t off = 0;
    float* resid  = ws + off; off += (size_t)NTOK * E;
    float* hidden = ws + off; off += (size_t)NTOK * E;
    float* xz     = ws + off; off += (size_t)NTOK * 2 * DI;
    float* xc     = ws + off; off += (size_t)NTOK * DI;
    float* xdb    = ws + off; off += (size_t)NTOK * 44;
    float* ylocal = ws + off; off += (size_t)NTOK * DI;
    float* dtcum  = ws + off; off += (size_t)NTOK * DI;
    float* hend   = ws + off; off += (size_t)BATCH * NCH * DI * S;
    float* hinit  = ws + off; off += (size_t)BATCH * NCH * DI * S;
    float* negA   = ws + off; off += (size_t)DEPTH * DI * S;
    // bf16 regions (as ushort); hn/xc_bf/y_bf live ranges are disjoint
    unsigned short* bf_buf = (unsigned short*)(ws + off); off += (size_t)NTOK * DI / 2;
    unsigned short* w_in  = (unsigned short*)(ws + off); off += (size_t)DEPTH * 2 * DI * E / 2;
    unsigned short* w_x   = (unsigned short*)(ws + off); off += (size_t)DEPTH * 44 * DI / 2 + 16;
    unsigned short* w_out = (unsigned short*)(ws + off); off += (size_t)DEPTH * E * DI / 2;

    unsigned short* hn_bf = bf_buf;   // [NTOK, E]
    unsigned short* xc_bf = bf_buf;   // [NTOK, DI]
    unsigned short* y_bf  = bf_buf;   // [NTOK, DI]

    // weight conversion + negA precompute (cheap, every launch)
    {
        int n1 = DEPTH * 2 * DI * E;
        k_cvt<<<(n1 + 255) / 256, 256, 0, stream>>>(in_proj_w, w_in, n1);
        int n2 = DEPTH * 44 * DI;
        k_cvt<<<(n2 + 255) / 256, 256, 0, stream>>>(x_proj_w, w_x, n2);
        int n3 = DEPTH * E * DI;
        k_cvt<<<(n3 + 255) / 256, 256, 0, stream>>>(out_proj_w, w_out, n3);
        int n4 = DEPTH * DI * S;
        k_preA<<<(n4 + 255) / 256, 256, 0, stream>>>(A_log, negA, n4);
    }

    // K0: embed
    k_embed<<<(NTOK * E) / 256, 256, 0, stream>>>(imgs, patch_w, patch_b, cls_token,
                                                  pos_embed, cnn_w, cnn_b, resid);

    for (int i = 0; i < DEPTH; i++) {
        if (i == 0)
            k_rmsnorm<false><<<NTOK / 4, 256, 0, stream>>>(hidden, resid, hn_bf, norm_w + i * E);
        else
            k_rmsnorm<true><<<NTOK / 4, 256, 0, stream>>>(hidden, resid, hn_bf, norm_w + i * E);

        // in_proj: [NTOK,192]bf16 x [768,192]bf16^T -> xz f32 [NTOK,768]
        {
            dim3 g((2 * DI) / 64, (NTOK + 127) / 128);
            k_gemm_bf16<128><<<g, 256, 0, stream>>>(hn_bf, w_in + (size_t)i * 2 * DI * E, xz,
                                                    NTOK, 2 * DI, E);
        }
        // causal conv4 + silu -> xc f32 + bf16
        k_conv<<<(NTOK * DI) / 256, 256, 0, stream>>>(xz, conv_w + (size_t)i * DI * 4,
                                                      conv_b + (size_t)i * DI, xc, xc_bf);
        // x_proj: [NTOK,384]bf16 x [44,384]bf16^T -> xdb f32 [NTOK,44]
        // BM=32 -> 401 blocks (vs 101 at BM=128): latency-bound kernel needs blocks
        {
            dim3 g(1, NTOK / 32);
            k_gemm_bf16<32><<<g, 256, 0, stream>>>(xc_bf, w_x + (size_t)i * 44 * DI, xdb,
                                                   NTOK, 44, DI);
        }
        // chunked scan: local scan (dt_proj fused) -> chunk combine -> parallel fixup
        {
            const float* nA = negA + (size_t)i * DI * S;
            dim3 g(NCH, BATCH);
            k_scanA<<<g, DI, 0, stream>>>(xc, xdb, nA, dt_proj_w + (size_t)i * DI * R,
                                          dt_proj_b + (size_t)i * DI, Dskip + (size_t)i * DI,
                                          ylocal, dtcum, hend);
            k_scanB<<<(BATCH * DI + 255) / 256, 256, 0, stream>>>(hend, dtcum, nA, hinit);
            k_fixup<<<(NTOK * DI + 255) / 256, 256, 0, stream>>>(xz, xdb, nA, hinit,
                                                                 ylocal, dtcum, y_bf);
        }
        // out_proj: [NTOK,384]bf16 x [192,384]bf16^T -> hidden f32 [NTOK,192]
        {
            dim3 g(E / 64, (NTOK + 63) / 64);
            k_gemm_bf16<64><<<g, 256, 0, stream>>>(y_bf, w_out + (size_t)i * E * DI, hidden,
                                                   NTOK, E, DI);
        }
    }

    k_head<<<BATCH, 64, 0, stream>>>(resid, hidden, norm_f_w, head_w, head_b, (float*)d_out);
}